// Round 5
// baseline (959.019 us; speedup 1.0000x reference)
//
#include <hip/hip_runtime.h>
#include <hip/hip_bf16.h>
#include <type_traits>

#define B_  8
#define LO_ 512
#define E_  768
#define H_  12
#define S_  2048

typedef __attribute__((ext_vector_type(8))) short bf16x8;
typedef __attribute__((ext_vector_type(4))) float f32x4;
#define MFMA16(a,b,c) __builtin_amdgcn_mfma_f32_16x16x32_bf16(a, b, c, 0, 0, 0)

__device__ inline short f2bf(float f) {
  __hip_bfloat16 h = __float2bfloat16(f);
  return *reinterpret_cast<short*>(&h);
}
__device__ inline float bf2f(short s) {
  unsigned int u = ((unsigned int)(unsigned short)s) << 16;
  return __uint_as_float(u);
}

// ================= MFMA GEMM: C[r][c] = sum_k A[r][k]*W[c][k] + bias[c] ==========
template <typename TC>
__global__ __launch_bounds__(256) void gemm_mfma(
    const float* __restrict__ A, const float* __restrict__ W,
    const float* __restrict__ bias, TC* __restrict__ C, int R)
{
  constexpr int N = 768, K = 768;
  __shared__ short As[64*72] __attribute__((aligned(16)));
  __shared__ short Ws[64*72] __attribute__((aligned(16)));
  const int tid = threadIdx.x, wv = tid >> 6, lane = tid & 63;
  const int quad = lane >> 4, l15 = lane & 15;
  const int r0 = blockIdx.x * 64, c0 = blockIdx.y * 64;
  const int srow = tid >> 2, sk = (tid & 3) * 16;

  f32x4 acc[4] = {};

  for (int k0 = 0; k0 < K; k0 += 64) {
    float a16[16], w16[16];
    const float4* ga = (const float4*)(A + (size_t)(r0 + srow) * K + k0 + sk);
    const float4* gw = (const float4*)(W + (size_t)(c0 + srow) * K + k0 + sk);
#pragma unroll
    for (int i = 0; i < 4; ++i) {
      float4 va = ga[i]; a16[4*i] = va.x; a16[4*i+1] = va.y; a16[4*i+2] = va.z; a16[4*i+3] = va.w;
      float4 vw = gw[i]; w16[4*i] = vw.x; w16[4*i+1] = vw.y; w16[4*i+2] = vw.z; w16[4*i+3] = vw.w;
    }
    bf16x8 pa[2], pw[2];
#pragma unroll
    for (int g = 0; g < 2; ++g)
#pragma unroll
      for (int i = 0; i < 8; ++i) { pa[g][i] = f2bf(a16[g*8+i]); pw[g][i] = f2bf(w16[g*8+i]); }
    __syncthreads();   // previous iteration's frag reads complete
    *(bf16x8*)&As[srow*72 + sk]     = pa[0];
    *(bf16x8*)&As[srow*72 + sk + 8] = pa[1];
    *(bf16x8*)&Ws[srow*72 + sk]     = pw[0];
    *(bf16x8*)&Ws[srow*72 + sk + 8] = pw[1];
    __syncthreads();

    bf16x8 af0 = *(const bf16x8*)&As[(wv*16 + l15)*72 +      quad*8];
    bf16x8 af1 = *(const bf16x8*)&As[(wv*16 + l15)*72 + 32 + quad*8];
#pragma unroll
    for (int ct = 0; ct < 4; ++ct) {
      bf16x8 bf0 = *(const bf16x8*)&Ws[(ct*16 + l15)*72 +      quad*8];
      bf16x8 bf1 = *(const bf16x8*)&Ws[(ct*16 + l15)*72 + 32 + quad*8];
      acc[ct] = MFMA16(af0, bf0, acc[ct]);
      acc[ct] = MFMA16(af1, bf1, acc[ct]);
    }
  }

#pragma unroll
  for (int ct = 0; ct < 4; ++ct) {
    const int col = c0 + ct*16 + l15;
    const float bv = bias[col];
#pragma unroll
    for (int r = 0; r < 4; ++r) {
      const int row = r0 + wv*16 + quad*4 + r;       // C layout: row=quad*4+reg, col=lane&15
      const float v = acc[ct][r] + bv;
      if constexpr (std::is_same_v<TC, float>) C[(size_t)row * N + col] = v;
      else                                     C[(size_t)row * N + col] = __float2bfloat16(v);
    }
  }
}

// ================= stats kernel: per-row softmax (m, 1/l) over full 2048 =========
// (round-2 version: named-register depth-1 pipeline + XCD swizzle — verified fast)
__device__ __forceinline__ void stats_load(
    const __hip_bfloat16* __restrict__ kq, const float* __restrict__ mb, int it,
    bf16x8 (&kb)[4][2], float (&mv)[4][4])
{
#pragma unroll
  for (int ct = 0; ct < 4; ++ct) {
    kb[ct][0] = *(const bf16x8*)(kq + (size_t)ct*16*E_);
    kb[ct][1] = *(const bf16x8*)(kq + (size_t)ct*16*E_ + 32);
#pragma unroll
    for (int r = 0; r < 4; ++r)
      mv[ct][r] = mb[(size_t)r*S_ + it*256 + ct*16];
  }
}

__device__ __forceinline__ void stats_compute(
    const bf16x8 (&qa)[2], const bf16x8 (&kb)[4][2], const float (&mv)[4][4],
    float (&m_l)[4], float (&l_l)[4])
{
  float v[4][4];
#pragma unroll
  for (int ct = 0; ct < 4; ++ct) {
    f32x4 sacc = {};
    sacc = MFMA16(qa[0], kb[ct][0], sacc);
    sacc = MFMA16(qa[1], kb[ct][1], sacc);
#pragma unroll
    for (int r = 0; r < 4; ++r) v[ct][r] = sacc[r]*0.125f + mv[ct][r];
  }
#pragma unroll
  for (int r = 0; r < 4; ++r) {
    const float cm = fmaxf(fmaxf(v[0][r], v[1][r]), fmaxf(v[2][r], v[3][r]));
    const float mn = fmaxf(m_l[r], cm);
    const float add = (__expf(v[0][r]-mn) + __expf(v[1][r]-mn))
                    + (__expf(v[2][r]-mn) + __expf(v[3][r]-mn));
    l_l[r] = l_l[r]*__expf(m_l[r]-mn) + add;
    m_l[r] = mn;
  }
}

__global__ __launch_bounds__(256) void attn_stats(
    const __hip_bfloat16* __restrict__ q1, const __hip_bfloat16* __restrict__ q2,
    const __hip_bfloat16* __restrict__ k1, const __hip_bfloat16* __restrict__ k2,
    const float* __restrict__ mask, float* __restrict__ stats)
{
  __shared__ float smm[4][16], sml[4][16];

  const int tid = threadIdx.x, wv = tid >> 6, lane = tid & 63;
  const int quad = lane >> 4, l15 = lane & 15;
  const int bid = blockIdx.x;
  const int Lid = (bid & 7) * 384 + (bid >> 3);
  const int qt = Lid & 31, h = (Lid >> 5) % 12, b = Lid / 384;
  const int r0 = qt * 16;

  bf16x8 qa0[2], qa1[2];
#pragma unroll
  for (int ks = 0; ks < 2; ++ks) {
    qa0[ks] = *(const bf16x8*)(q1 + ((size_t)(b*LO_ + r0 + l15))*E_ + h*64 + ks*32 + quad*8);
    qa1[ks] = *(const bf16x8*)(q2 + ((size_t)(b*LO_ + r0 + l15))*E_ + h*64 + ks*32 + quad*8);
  }

  const float* mb = mask + (size_t)(r0 + quad*4)*S_ + wv*64 + l15;
  const __hip_bfloat16* kp1 = k1 + ((size_t)(b*1024 + wv*64 + l15))*E_ + h*64 + quad*8;
  const __hip_bfloat16* kp2 = k2 + ((size_t)(b*1024 + wv*64 + l15))*E_ + h*64 + quad*8;

  float m_l[4] = {-3.0e38f, -3.0e38f, -3.0e38f, -3.0e38f};
  float l_l[4] = {};

  bf16x8 kA[4][2], kB[4][2];
  float  mA[4][4], mB[4][4];

  stats_load(kp1 + (size_t)0*256*E_, mb, 0, kA, mA);
  stats_load(kp1 + (size_t)1*256*E_, mb, 1, kB, mB);
  stats_compute(qa0, kA, mA, m_l, l_l);
  stats_load(kp1 + (size_t)2*256*E_, mb, 2, kA, mA);
  stats_compute(qa0, kB, mB, m_l, l_l);
  stats_load(kp1 + (size_t)3*256*E_, mb, 3, kB, mB);
  stats_compute(qa0, kA, mA, m_l, l_l);
  stats_load(kp2 + (size_t)0*256*E_, mb, 4, kA, mA);
  stats_compute(qa0, kB, mB, m_l, l_l);
  stats_load(kp2 + (size_t)1*256*E_, mb, 5, kB, mB);
  stats_compute(qa1, kA, mA, m_l, l_l);
  stats_load(kp2 + (size_t)2*256*E_, mb, 6, kA, mA);
  stats_compute(qa1, kB, mB, m_l, l_l);
  stats_load(kp2 + (size_t)3*256*E_, mb, 7, kB, mB);
  stats_compute(qa1, kA, mA, m_l, l_l);
  stats_compute(qa1, kB, mB, m_l, l_l);

#pragma unroll
  for (int off = 1; off < 16; off <<= 1) {
#pragma unroll
    for (int r = 0; r < 4; ++r) {
      const float mo = __shfl_xor(m_l[r], off, 64);
      const float lo = __shfl_xor(l_l[r], off, 64);
      const float mn = fmaxf(m_l[r], mo);
      l_l[r] = l_l[r]*__expf(m_l[r]-mn) + lo*__expf(mo-mn);
      m_l[r] = mn;
    }
  }
  if (l15 == 0) {
#pragma unroll
    for (int r = 0; r < 4; ++r) { smm[wv][quad*4+r] = m_l[r]; sml[wv][quad*4+r] = l_l[r]; }
  }
  __syncthreads();
  if (tid < 16) {
    float m = smm[0][tid], l = sml[0][tid];
#pragma unroll
    for (int ww = 1; ww < 4; ++ww) {
      const float mo = smm[ww][tid], lo = sml[ww][tid];
      const float mn = fmaxf(m, mo);
      l = l*__expf(m-mn) + lo*__expf(mo-mn);
      m = mn;
    }
    const size_t idx = (((size_t)(b*H_ + h))*LO_ + r0 + tid) * 2;
    stats[idx] = m; stats[idx+1] = 1.0f / l;
  }
}

// ================= main attention v4 ============================================
// grid: (b, qt16, src, keyhalf) = 1024 blocks, 512 thr = 8 waves, LDS 29952 B.
// vs v3: (1) XCD-aware swizzle — all 128 blocks of batch b land on XCD b, so the
// shared K/V slices live in ONE L2 instead of being fetched into all 8 (FETCH was
// 318 MB ≈ 48 MB unique × 7); (2) key-split ×2 — each block does 512 keys (4 cp),
// grid 1024 → 4 blocks/CU → 32 waves/CU. Rationale: the compiler drains vmcnt(0)
// at every barrier, so in-register prefetch can never hide load latency here; only
// other blocks' waves can (TLP). avg key-columns are disjoint per key-half (plain
// stores); ctx is already atomicAdd. __launch_bounds__(512,8) pins VGPR<=64.
#define OFF_VT   0
#define OFF_PST  17408
#define OFF_OBUF 21760
#define SMEM_MAIN 29952

__global__ __launch_bounds__(512, 8) void attn_main(
    const __hip_bfloat16* __restrict__ q1, const __hip_bfloat16* __restrict__ q2,
    const __hip_bfloat16* __restrict__ k1, const __hip_bfloat16* __restrict__ v1,
    const __hip_bfloat16* __restrict__ k2, const __hip_bfloat16* __restrict__ v2,
    const float* __restrict__ mask, const float* __restrict__ stats,
    float* __restrict__ ctx, float* __restrict__ avg)
{
  extern __shared__ char smem[];
  short* vT   = (short*)(smem + OFF_VT);     // [64 dims][136] bf16, key-chunk swizzled
  short* pst  = (short*)(smem + OFF_PST);    // [16][136] bf16
  float* obuf = (float*)(smem + OFF_OBUF);   // [8][256]

  const int tid = threadIdx.x, wv = tid >> 6, lane = tid & 63;
  const int quad = lane >> 4, l15 = lane & 15;
  // XCD swizzle: 1024 blocks = 8 XCD-chunks of 128; batch b == XCD index.
  const int bid = blockIdx.x;
  const int Lid = (bid & 7) * 128 + (bid >> 3);
  const int b = Lid >> 7;
  const int inner = Lid & 127;
  const int src = inner & 1, ks = (inner >> 1) & 1, qt = inner >> 2;
  const int r0 = qt * 16;
  const int kb0 = b*1024 + ks*512;   // first global key row for this block
  const __hip_bfloat16* qws = src ? q2 : q1;
  const __hip_bfloat16* kws = src ? k2 : k1;
  const __hip_bfloat16* vws = src ? v2 : v1;

  const int cpr = wv >> 2;   // 64-key half of the staged 128
  const int ct  = wv & 3;    // 16-wide dim tile
  const int nb  = cpr*64 + ct*16;

  // V staging coords: key row = tid>>2 (0..127), dim base = (tid&3)*16
  const int vrow = tid >> 2, vc16 = (tid & 3) * 16;
  const int vbase = vc16*136 + (((vrow >> 3) ^ ((tid & 3) << 1)) << 3) + (vrow & 7);
  const int dimv = ct*16 + l15;
  const int vr0 = dimv*136 + (((cpr*8 +     quad) ^ (ct << 1)) << 3);
  const int vr1 = dimv*136 + (((cpr*8 + 4 + quad) ^ (ct << 1)) << 3);

  // ---- mask: head-independent, this block's 4 cp chunks, packed bf16 in regs ----
  unsigned int mpk[8];
  {
    const float* mptr = mask + (size_t)(r0 + quad*4)*S_ + src*1024 + ks*512 + nb + l15;
#pragma unroll
    for (int cp = 0; cp < 4; ++cp) {
      const float m0 = mptr[(size_t)0*S_ + cp*128];
      const float m1 = mptr[(size_t)1*S_ + cp*128];
      const float m2 = mptr[(size_t)2*S_ + cp*128];
      const float m3 = mptr[(size_t)3*S_ + cp*128];
      mpk[cp*2]   = (unsigned int)(unsigned short)f2bf(m0) | ((unsigned int)(unsigned short)f2bf(m1) << 16);
      mpk[cp*2+1] = (unsigned int)(unsigned short)f2bf(m2) | ((unsigned int)(unsigned short)f2bf(m3) << 16);
    }
  }

  float pacc[4][4] = {};   // [cp][r] — cp always a literal (unrolled macro)

  bf16x8 kA0, kA1, kB0, kB1, vA0, vA1, vB0, vB1;

#define CP_BODY(CP, KC0, KC1, KN0, KN1, VC0, VC1, VN0, VN1)                          \
  {                                                                                  \
    __syncthreads();  /* prev cp's PV reads of vT/pst complete */                    \
    _Pragma("unroll")                                                                \
    for (int i = 0; i < 8; ++i) vT[vbase + i*136]     = VC0[i];                      \
    _Pragma("unroll")                                                                \
    for (int i = 0; i < 8; ++i) vT[vbase + (i+8)*136] = VC1[i];                      \
    if ((CP) < 3) {  /* prefetch next chunk's K/V */                                 \
      const __hip_bfloat16* kp = kws + ((size_t)(kb0 + ((CP)+1)*128 + nb + l15))*E_ + h*64 + quad*8; \
      KN0 = *(const bf16x8*)kp;                                                      \
      KN1 = *(const bf16x8*)(kp + 32);                                               \
      const bf16x8* gv = (const bf16x8*)(vws + ((size_t)(kb0 + ((CP)+1)*128 + vrow))*E_ + h*64 + vc16); \
      VN0 = gv[0]; VN1 = gv[1];                                                      \
    }                                                                                \
    {                                                                                \
      f32x4 sacc = {};                                                               \
      sacc = MFMA16(qa0, KC0, sacc);                                                 \
      sacc = MFMA16(qa1, KC1, sacc);                                                 \
      const unsigned int w0 = mpk[(CP)*2], w1 = mpk[(CP)*2+1];                       \
      float mr[4];                                                                   \
      mr[0] = bf2f((short)(w0 & 0xffff)); mr[1] = bf2f((short)(w0 >> 16));           \
      mr[2] = bf2f((short)(w1 & 0xffff)); mr[3] = bf2f((short)(w1 >> 16));           \
      _Pragma("unroll")                                                              \
      for (int r = 0; r < 4; ++r) {                                                  \
        const float p = __expf(sacc[r]*0.125f + mr[r] - m_r[r]) * il_r[r];           \
        pacc[CP][r] += p;                                                            \
        pst[(quad*4 + r)*136 + nb + l15] = f2bf(p);                                  \
      }                                                                              \
    }                                                                                \
    __syncthreads();  /* vT + pst visible */                                         \
    {                                                                                \
      const bf16x8 pa0 = *(const bf16x8*)&pst[l15*136 + cpr*64 +      quad*8];       \
      const bf16x8 pa1 = *(const bf16x8*)&pst[l15*136 + cpr*64 + 32 + quad*8];       \
      const bf16x8 vb0 = *(const bf16x8*)&vT[vr0];                                   \
      const bf16x8 vb1 = *(const bf16x8*)&vT[vr1];                                   \
      oacc = MFMA16(pa0, vb0, oacc);                                                 \
      oacc = MFMA16(pa1, vb1, oacc);                                                 \
    }                                                                                \
  }

#pragma unroll 1
  for (int h = 0; h < H_; ++h) {
    // Q fragments + stats direct from global
    const __hip_bfloat16* qp = qws + ((size_t)(b*LO_ + r0 + l15))*E_ + h*64 + quad*8;
    const bf16x8 qa0 = *(const bf16x8*)qp;
    const bf16x8 qa1 = *(const bf16x8*)(qp + 32);

    float m_r[4], il_r[4];
#pragma unroll
    for (int r = 0; r < 4; ++r) {
      const size_t idx = (((size_t)(b*H_ + h))*LO_ + r0 + quad*4 + r) * 2;
      m_r[r] = stats[idx]; il_r[r] = stats[idx+1];
    }

    // preload K(0), V(0) for this head
    {
      const __hip_bfloat16* kp = kws + ((size_t)(kb0 + nb + l15))*E_ + h*64 + quad*8;
      kA0 = *(const bf16x8*)kp;
      kA1 = *(const bf16x8*)(kp + 32);
      const bf16x8* gv = (const bf16x8*)(vws + ((size_t)(kb0 + vrow))*E_ + h*64 + vc16);
      vA0 = gv[0]; vA1 = gv[1];
    }

    f32x4 oacc = {};

    CP_BODY(0, kA0, kA1, kB0, kB1, vA0, vA1, vB0, vB1)
    CP_BODY(1, kB0, kB1, kA0, kA1, vB0, vB1, vA0, vA1)
    CP_BODY(2, kA0, kA1, kB0, kB1, vA0, vA1, vB0, vB1)
    CP_BODY(3, kB0, kB1, kA0, kA1, vB0, vB1, vA0, vA1)

    // ---- merge wave pairs (wv, wv+4) and accumulate ctx ----
    __syncthreads();   // PV reads of vT/pst done before obuf overwrites nothing; order waves
#pragma unroll
    for (int r = 0; r < 4; ++r) obuf[wv*256 + r*64 + lane] = oacc[r];
    __syncthreads();
#pragma unroll
    for (int e0 = 0; e0 < 2; ++e0) {
      const int e = tid + e0*512;
      const int row = e >> 6, dim = e & 63;
      const int idx = (row & 3)*64 + (row >> 2)*16 + (dim & 15);
      const float v = obuf[(dim >> 4)*256 + idx] + obuf[((dim >> 4) + 4)*256 + idx];
      atomicAdd(&ctx[((size_t)(b*LO_ + r0 + row))*E_ + h*64 + dim], v);
    }
  }
#undef CP_BODY

  // ---- write head-averaged attention (fp32) from registers (disjoint columns) ----
  {
    constexpr float invH = 1.0f / 12.0f;
#pragma unroll
    for (int cp = 0; cp < 4; ++cp)
#pragma unroll
      for (int r = 0; r < 4; ++r)
        avg[(size_t)(b*LO_ + r0 + quad*4 + r)*S_ + src*1024 + ks*512 + cp*128 + nb + l15]
            = pacc[cp][r] * invH;
  }
}

// ================= launch =================
extern "C" void kernel_launch(void* const* d_in, const int* in_sizes, int n_in,
                              void* d_out, int out_size, void* d_ws, size_t ws_size,
                              hipStream_t stream) {
  const float* V    = (const float*)d_in[0];
  const float* Lm   = (const float*)d_in[1];
  const float* O    = (const float*)d_in[2];
  const float* mask = (const float*)d_in[3];
  const float* w1   = (const float*)d_in[4];
  const float* b1   = (const float*)d_in[5];
  const float* w2   = (const float*)d_in[6];
  const float* b2   = (const float*)d_in[7];
  const float* ow   = (const float*)d_in[8];
  const float* ob   = (const float*)d_in[9];
  float* out = (float*)d_out;

  __hip_bfloat16* ws  = (__hip_bfloat16*)d_ws;
  __hip_bfloat16* q1  = ws;
  __hip_bfloat16* q2  = q1 + (size_t)4096*768;
  __hip_bfloat16* k1  = q2 + (size_t)4096*768;
  __hip_bfloat16* v1  = k1 + (size_t)8192*768;
  __hip_bfloat16* k2  = v1 + (size_t)8192*768;
  __hip_bfloat16* v2  = k2 + (size_t)8192*768;
  float* ctx   = (float*)(v2 + (size_t)8192*768);
  float* stats = ctx + (size_t)4096*768;

  hipMemsetAsync(ctx, 0, (size_t)4096*768*4, stream);

  dim3 blk(256);
  gemm_mfma<__hip_bfloat16><<<dim3(64, 12),  blk, 0, stream>>>(O,  w1,             b1,        q1, 4096);
  gemm_mfma<__hip_bfloat16><<<dim3(64, 12),  blk, 0, stream>>>(O,  w2,             b2,        q2, 4096);
  gemm_mfma<__hip_bfloat16><<<dim3(128, 12), blk, 0, stream>>>(V,  w1 + 768*768,   b1 + 768,  k1, 8192);
  gemm_mfma<__hip_bfloat16><<<dim3(128, 12), blk, 0, stream>>>(V,  w1 + 2*768*768, b1 + 1536, v1, 8192);
  gemm_mfma<__hip_bfloat16><<<dim3(128, 12), blk, 0, stream>>>(Lm, w2 + 768*768,   b2 + 768,  k2, 8192);
  gemm_mfma<__hip_bfloat16><<<dim3(128, 12), blk, 0, stream>>>(Lm, w2 + 2*768*768, b2 + 1536, v2, 8192);

  attn_stats<<<dim3(3072), blk, 0, stream>>>(q1, q2, k1, k2, mask, stats);

  hipFuncSetAttribute((const void*)attn_main, hipFuncAttributeMaxDynamicSharedMemorySize, SMEM_MAIN);
  attn_main<<<dim3(1024), dim3(512), SMEM_MAIN, stream>>>(q1, q2, k1, v1, k2, v2, mask, stats,
                                                          ctx, out + (size_t)4096*768);

  gemm_mfma<float><<<dim3(64, 12), blk, 0, stream>>>(ctx, ow, ob, out, 4096);
}

// Round 6
// 651.099 us; speedup vs baseline: 1.4729x; 1.4729x over previous
//
#include <hip/hip_runtime.h>
#include <hip/hip_bf16.h>
#include <type_traits>

#define B_  8
#define LO_ 512
#define E_  768
#define H_  12
#define S_  2048

typedef __attribute__((ext_vector_type(8))) short bf16x8;
typedef __attribute__((ext_vector_type(4))) float f32x4;
#define MFMA16(a,b,c) __builtin_amdgcn_mfma_f32_16x16x32_bf16(a, b, c, 0, 0, 0)

__device__ inline short f2bf(float f) {
  __hip_bfloat16 h = __float2bfloat16(f);
  return *reinterpret_cast<short*>(&h);
}
__device__ inline float bf2f(short s) {
  unsigned int u = ((unsigned int)(unsigned short)s) << 16;
  return __uint_as_float(u);
}

// ================= MFMA GEMM: C[r][c] = sum_k A[r][k]*W[c][k] + bias[c] ==========
template <typename TC>
__global__ __launch_bounds__(256) void gemm_mfma(
    const float* __restrict__ A, const float* __restrict__ W,
    const float* __restrict__ bias, TC* __restrict__ C, int R)
{
  constexpr int N = 768, K = 768;
  __shared__ short As[64*72] __attribute__((aligned(16)));
  __shared__ short Ws[64*72] __attribute__((aligned(16)));
  const int tid = threadIdx.x, wv = tid >> 6, lane = tid & 63;
  const int quad = lane >> 4, l15 = lane & 15;
  const int r0 = blockIdx.x * 64, c0 = blockIdx.y * 64;
  const int srow = tid >> 2, sk = (tid & 3) * 16;

  f32x4 acc[4] = {};

  for (int k0 = 0; k0 < K; k0 += 64) {
    float a16[16], w16[16];
    const float4* ga = (const float4*)(A + (size_t)(r0 + srow) * K + k0 + sk);
    const float4* gw = (const float4*)(W + (size_t)(c0 + srow) * K + k0 + sk);
#pragma unroll
    for (int i = 0; i < 4; ++i) {
      float4 va = ga[i]; a16[4*i] = va.x; a16[4*i+1] = va.y; a16[4*i+2] = va.z; a16[4*i+3] = va.w;
      float4 vw = gw[i]; w16[4*i] = vw.x; w16[4*i+1] = vw.y; w16[4*i+2] = vw.z; w16[4*i+3] = vw.w;
    }
    bf16x8 pa[2], pw[2];
#pragma unroll
    for (int g = 0; g < 2; ++g)
#pragma unroll
      for (int i = 0; i < 8; ++i) { pa[g][i] = f2bf(a16[g*8+i]); pw[g][i] = f2bf(w16[g*8+i]); }
    __syncthreads();   // previous iteration's frag reads complete
    *(bf16x8*)&As[srow*72 + sk]     = pa[0];
    *(bf16x8*)&As[srow*72 + sk + 8] = pa[1];
    *(bf16x8*)&Ws[srow*72 + sk]     = pw[0];
    *(bf16x8*)&Ws[srow*72 + sk + 8] = pw[1];
    __syncthreads();

    bf16x8 af0 = *(const bf16x8*)&As[(wv*16 + l15)*72 +      quad*8];
    bf16x8 af1 = *(const bf16x8*)&As[(wv*16 + l15)*72 + 32 + quad*8];
#pragma unroll
    for (int ct = 0; ct < 4; ++ct) {
      bf16x8 bf0 = *(const bf16x8*)&Ws[(ct*16 + l15)*72 +      quad*8];
      bf16x8 bf1 = *(const bf16x8*)&Ws[(ct*16 + l15)*72 + 32 + quad*8];
      acc[ct] = MFMA16(af0, bf0, acc[ct]);
      acc[ct] = MFMA16(af1, bf1, acc[ct]);
    }
  }

#pragma unroll
  for (int ct = 0; ct < 4; ++ct) {
    const int col = c0 + ct*16 + l15;
    const float bv = bias[col];
#pragma unroll
    for (int r = 0; r < 4; ++r) {
      const int row = r0 + wv*16 + quad*4 + r;       // C layout: row=quad*4+reg, col=lane&15
      const float v = acc[ct][r] + bv;
      if constexpr (std::is_same_v<TC, float>) C[(size_t)row * N + col] = v;
      else                                     C[(size_t)row * N + col] = __float2bfloat16(v);
    }
  }
}

// ================= stats kernel: per-row softmax (m, 1/l) over full 2048 =========
// (round-2 version: named-register depth-1 pipeline + XCD swizzle — verified fast)
__device__ __forceinline__ void stats_load(
    const __hip_bfloat16* __restrict__ kq, const float* __restrict__ mb, int it,
    bf16x8 (&kb)[4][2], float (&mv)[4][4])
{
#pragma unroll
  for (int ct = 0; ct < 4; ++ct) {
    kb[ct][0] = *(const bf16x8*)(kq + (size_t)ct*16*E_);
    kb[ct][1] = *(const bf16x8*)(kq + (size_t)ct*16*E_ + 32);
#pragma unroll
    for (int r = 0; r < 4; ++r)
      mv[ct][r] = mb[(size_t)r*S_ + it*256 + ct*16];
  }
}

__device__ __forceinline__ void stats_compute(
    const bf16x8 (&qa)[2], const bf16x8 (&kb)[4][2], const float (&mv)[4][4],
    float (&m_l)[4], float (&l_l)[4])
{
  float v[4][4];
#pragma unroll
  for (int ct = 0; ct < 4; ++ct) {
    f32x4 sacc = {};
    sacc = MFMA16(qa[0], kb[ct][0], sacc);
    sacc = MFMA16(qa[1], kb[ct][1], sacc);
#pragma unroll
    for (int r = 0; r < 4; ++r) v[ct][r] = sacc[r]*0.125f + mv[ct][r];
  }
#pragma unroll
  for (int r = 0; r < 4; ++r) {
    const float cm = fmaxf(fmaxf(v[0][r], v[1][r]), fmaxf(v[2][r], v[3][r]));
    const float mn = fmaxf(m_l[r], cm);
    const float add = (__expf(v[0][r]-mn) + __expf(v[1][r]-mn))
                    + (__expf(v[2][r]-mn) + __expf(v[3][r]-mn));
    l_l[r] = l_l[r]*__expf(m_l[r]-mn) + add;
    m_l[r] = mn;
  }
}

__global__ __launch_bounds__(256) void attn_stats(
    const __hip_bfloat16* __restrict__ q1, const __hip_bfloat16* __restrict__ q2,
    const __hip_bfloat16* __restrict__ k1, const __hip_bfloat16* __restrict__ k2,
    const float* __restrict__ mask, float* __restrict__ stats)
{
  __shared__ float smm[4][16], sml[4][16];

  const int tid = threadIdx.x, wv = tid >> 6, lane = tid & 63;
  const int quad = lane >> 4, l15 = lane & 15;
  const int bid = blockIdx.x;
  const int Lid = (bid & 7) * 384 + (bid >> 3);
  const int qt = Lid & 31, h = (Lid >> 5) % 12, b = Lid / 384;
  const int r0 = qt * 16;

  bf16x8 qa0[2], qa1[2];
#pragma unroll
  for (int ks = 0; ks < 2; ++ks) {
    qa0[ks] = *(const bf16x8*)(q1 + ((size_t)(b*LO_ + r0 + l15))*E_ + h*64 + ks*32 + quad*8);
    qa1[ks] = *(const bf16x8*)(q2 + ((size_t)(b*LO_ + r0 + l15))*E_ + h*64 + ks*32 + quad*8);
  }

  const float* mb = mask + (size_t)(r0 + quad*4)*S_ + wv*64 + l15;
  const __hip_bfloat16* kp1 = k1 + ((size_t)(b*1024 + wv*64 + l15))*E_ + h*64 + quad*8;
  const __hip_bfloat16* kp2 = k2 + ((size_t)(b*1024 + wv*64 + l15))*E_ + h*64 + quad*8;

  float m_l[4] = {-3.0e38f, -3.0e38f, -3.0e38f, -3.0e38f};
  float l_l[4] = {};

  bf16x8 kA[4][2], kB[4][2];
  float  mA[4][4], mB[4][4];

  stats_load(kp1 + (size_t)0*256*E_, mb, 0, kA, mA);
  stats_load(kp1 + (size_t)1*256*E_, mb, 1, kB, mB);
  stats_compute(qa0, kA, mA, m_l, l_l);
  stats_load(kp1 + (size_t)2*256*E_, mb, 2, kA, mA);
  stats_compute(qa0, kB, mB, m_l, l_l);
  stats_load(kp1 + (size_t)3*256*E_, mb, 3, kB, mB);
  stats_compute(qa0, kA, mA, m_l, l_l);
  stats_load(kp2 + (size_t)0*256*E_, mb, 4, kA, mA);
  stats_compute(qa0, kB, mB, m_l, l_l);
  stats_load(kp2 + (size_t)1*256*E_, mb, 5, kB, mB);
  stats_compute(qa1, kA, mA, m_l, l_l);
  stats_load(kp2 + (size_t)2*256*E_, mb, 6, kA, mA);
  stats_compute(qa1, kB, mB, m_l, l_l);
  stats_load(kp2 + (size_t)3*256*E_, mb, 7, kB, mB);
  stats_compute(qa1, kA, mA, m_l, l_l);
  stats_compute(qa1, kB, mB, m_l, l_l);

#pragma unroll
  for (int off = 1; off < 16; off <<= 1) {
#pragma unroll
    for (int r = 0; r < 4; ++r) {
      const float mo = __shfl_xor(m_l[r], off, 64);
      const float lo = __shfl_xor(l_l[r], off, 64);
      const float mn = fmaxf(m_l[r], mo);
      l_l[r] = l_l[r]*__expf(m_l[r]-mn) + lo*__expf(mo-mn);
      m_l[r] = mn;
    }
  }
  if (l15 == 0) {
#pragma unroll
    for (int r = 0; r < 4; ++r) { smm[wv][quad*4+r] = m_l[r]; sml[wv][quad*4+r] = l_l[r]; }
  }
  __syncthreads();
  if (tid < 16) {
    float m = smm[0][tid], l = sml[0][tid];
#pragma unroll
    for (int ww = 1; ww < 4; ++ww) {
      const float mo = smm[ww][tid], lo = sml[ww][tid];
      const float mn = fmaxf(m, mo);
      l = l*__expf(m-mn) + lo*__expf(mo-mn);
      m = mn;
    }
    const size_t idx = (((size_t)(b*H_ + h))*LO_ + r0 + tid) * 2;
    stats[idx] = m; stats[idx+1] = 1.0f / l;
  }
}

// ================= main attention v5 ============================================
// grid: (b, qt16, src, keyhalf) = 1024 blocks, 512 thr = 8 waves, LDS 29952 B.
// vs v4: __launch_bounds__(512,4) — v4's (512,8) forced VGPR=32 and the ~80-reg
// body spilled to scratch (WRITE_SIZE 97→872 MB, 2× slower). (512,4) gives budget
// 128; v3 compiled to 64 under the same bound, and 64 ⇒ 8 waves/SIMD ⇒ the
// 4 blocks/CU the key-split grid provides. K prefetch regs dropped (16 VGPRs):
// K is loaded inline at the top of the cp body — issued before the 16 V ds_writes,
// consumed after, so L2 latency overlaps the LDS stores + TLP. XCD swizzle and
// key-split x2 retained from v4 (untested there due to spill masking).
#define OFF_VT   0
#define OFF_PST  17408
#define OFF_OBUF 21760
#define SMEM_MAIN 29952

__global__ __launch_bounds__(512, 4) void attn_main(
    const __hip_bfloat16* __restrict__ q1, const __hip_bfloat16* __restrict__ q2,
    const __hip_bfloat16* __restrict__ k1, const __hip_bfloat16* __restrict__ v1,
    const __hip_bfloat16* __restrict__ k2, const __hip_bfloat16* __restrict__ v2,
    const float* __restrict__ mask, const float* __restrict__ stats,
    float* __restrict__ ctx, float* __restrict__ avg)
{
  extern __shared__ char smem[];
  short* vT   = (short*)(smem + OFF_VT);     // [64 dims][136] bf16, key-chunk swizzled
  short* pst  = (short*)(smem + OFF_PST);    // [16][136] bf16
  float* obuf = (float*)(smem + OFF_OBUF);   // [8][256]

  const int tid = threadIdx.x, wv = tid >> 6, lane = tid & 63;
  const int quad = lane >> 4, l15 = lane & 15;
  // XCD swizzle: 1024 blocks = 8 XCD-chunks of 128; batch b == XCD index.
  const int bid = blockIdx.x;
  const int Lid = (bid & 7) * 128 + (bid >> 3);
  const int b = Lid >> 7;
  const int inner = Lid & 127;
  const int src = inner & 1, ks = (inner >> 1) & 1, qt = inner >> 2;
  const int r0 = qt * 16;
  const int kb0 = b*1024 + ks*512;   // first global key row for this block
  const __hip_bfloat16* qws = src ? q2 : q1;
  const __hip_bfloat16* kws = src ? k2 : k1;
  const __hip_bfloat16* vws = src ? v2 : v1;

  const int cpr = wv >> 2;   // 64-key half of the staged 128
  const int ct  = wv & 3;    // 16-wide dim tile
  const int nb  = cpr*64 + ct*16;

  // V staging coords: key row = tid>>2 (0..127), dim base = (tid&3)*16
  const int vrow = tid >> 2, vc16 = (tid & 3) * 16;
  const int vbase = vc16*136 + (((vrow >> 3) ^ ((tid & 3) << 1)) << 3) + (vrow & 7);
  const int dimv = ct*16 + l15;
  const int vr0 = dimv*136 + (((cpr*8 +     quad) ^ (ct << 1)) << 3);
  const int vr1 = dimv*136 + (((cpr*8 + 4 + quad) ^ (ct << 1)) << 3);

  // ---- mask: head-independent, this block's 4 cp chunks, packed bf16 in regs ----
  unsigned int mpk[8];
  {
    const float* mptr = mask + (size_t)(r0 + quad*4)*S_ + src*1024 + ks*512 + nb + l15;
#pragma unroll
    for (int cp = 0; cp < 4; ++cp) {
      const float m0 = mptr[(size_t)0*S_ + cp*128];
      const float m1 = mptr[(size_t)1*S_ + cp*128];
      const float m2 = mptr[(size_t)2*S_ + cp*128];
      const float m3 = mptr[(size_t)3*S_ + cp*128];
      mpk[cp*2]   = (unsigned int)(unsigned short)f2bf(m0) | ((unsigned int)(unsigned short)f2bf(m1) << 16);
      mpk[cp*2+1] = (unsigned int)(unsigned short)f2bf(m2) | ((unsigned int)(unsigned short)f2bf(m3) << 16);
    }
  }

  float pacc[4][4] = {};   // [cp][r] — cp always a literal (unrolled macro)

  bf16x8 vA0, vA1, vB0, vB1;

#define CP_BODY(CP, VC0, VC1, VN0, VN1)                                              \
  {                                                                                  \
    __syncthreads();  /* prev cp's PV reads of vT/pst complete */                    \
    /* K inline: issue load first, consume after the ds_writes below */              \
    const __hip_bfloat16* kp = kws + ((size_t)(kb0 + (CP)*128 + nb + l15))*E_ + h*64 + quad*8; \
    const bf16x8 kc0 = *(const bf16x8*)kp;                                           \
    const bf16x8 kc1 = *(const bf16x8*)(kp + 32);                                    \
    _Pragma("unroll")                                                                \
    for (int i = 0; i < 8; ++i) vT[vbase + i*136]     = VC0[i];                      \
    _Pragma("unroll")                                                                \
    for (int i = 0; i < 8; ++i) vT[vbase + (i+8)*136] = VC1[i];                      \
    if ((CP) < 3) {  /* prefetch next chunk's V */                                   \
      const bf16x8* gv = (const bf16x8*)(vws + ((size_t)(kb0 + ((CP)+1)*128 + vrow))*E_ + h*64 + vc16); \
      VN0 = gv[0]; VN1 = gv[1];                                                      \
    }                                                                                \
    {                                                                                \
      f32x4 sacc = {};                                                               \
      sacc = MFMA16(qa0, kc0, sacc);                                                 \
      sacc = MFMA16(qa1, kc1, sacc);                                                 \
      const unsigned int w0 = mpk[(CP)*2], w1 = mpk[(CP)*2+1];                       \
      float mr[4];                                                                   \
      mr[0] = bf2f((short)(w0 & 0xffff)); mr[1] = bf2f((short)(w0 >> 16));           \
      mr[2] = bf2f((short)(w1 & 0xffff)); mr[3] = bf2f((short)(w1 >> 16));           \
      _Pragma("unroll")                                                              \
      for (int r = 0; r < 4; ++r) {                                                  \
        const float p = __expf(sacc[r]*0.125f + mr[r] - m_r[r]) * il_r[r];           \
        pacc[CP][r] += p;                                                            \
        pst[(quad*4 + r)*136 + nb + l15] = f2bf(p);                                  \
      }                                                                              \
    }                                                                                \
    __syncthreads();  /* vT + pst visible */                                         \
    {                                                                                \
      const bf16x8 pa0 = *(const bf16x8*)&pst[l15*136 + cpr*64 +      quad*8];       \
      const bf16x8 pa1 = *(const bf16x8*)&pst[l15*136 + cpr*64 + 32 + quad*8];       \
      const bf16x8 vb0 = *(const bf16x8*)&vT[vr0];                                   \
      const bf16x8 vb1 = *(const bf16x8*)&vT[vr1];                                   \
      oacc = MFMA16(pa0, vb0, oacc);                                                 \
      oacc = MFMA16(pa1, vb1, oacc);                                                 \
    }                                                                                \
  }

#pragma unroll 1
  for (int h = 0; h < H_; ++h) {
    // Q fragments + stats direct from global
    const __hip_bfloat16* qp = qws + ((size_t)(b*LO_ + r0 + l15))*E_ + h*64 + quad*8;
    const bf16x8 qa0 = *(const bf16x8*)qp;
    const bf16x8 qa1 = *(const bf16x8*)(qp + 32);

    float m_r[4], il_r[4];
#pragma unroll
    for (int r = 0; r < 4; ++r) {
      const size_t idx = (((size_t)(b*H_ + h))*LO_ + r0 + quad*4 + r) * 2;
      m_r[r] = stats[idx]; il_r[r] = stats[idx+1];
    }

    // preload V(0) for this head
    {
      const bf16x8* gv = (const bf16x8*)(vws + ((size_t)(kb0 + vrow))*E_ + h*64 + vc16);
      vA0 = gv[0]; vA1 = gv[1];
    }

    f32x4 oacc = {};

    CP_BODY(0, vA0, vA1, vB0, vB1)
    CP_BODY(1, vB0, vB1, vA0, vA1)
    CP_BODY(2, vA0, vA1, vB0, vB1)
    CP_BODY(3, vB0, vB1, vA0, vA1)

    // ---- merge wave pairs (wv, wv+4) and accumulate ctx ----
    __syncthreads();   // PV reads of vT/pst done; order waves before obuf writes
#pragma unroll
    for (int r = 0; r < 4; ++r) obuf[wv*256 + r*64 + lane] = oacc[r];
    __syncthreads();
#pragma unroll
    for (int e0 = 0; e0 < 2; ++e0) {
      const int e = tid + e0*512;
      const int row = e >> 6, dim = e & 63;
      const int idx = (row & 3)*64 + (row >> 2)*16 + (dim & 15);
      const float v = obuf[(dim >> 4)*256 + idx] + obuf[((dim >> 4) + 4)*256 + idx];
      atomicAdd(&ctx[((size_t)(b*LO_ + r0 + row))*E_ + h*64 + dim], v);
    }
  }
#undef CP_BODY

  // ---- write head-averaged attention (fp32) from registers (disjoint columns) ----
  {
    constexpr float invH = 1.0f / 12.0f;
#pragma unroll
    for (int cp = 0; cp < 4; ++cp)
#pragma unroll
      for (int r = 0; r < 4; ++r)
        avg[(size_t)(b*LO_ + r0 + quad*4 + r)*S_ + src*1024 + ks*512 + cp*128 + nb + l15]
            = pacc[cp][r] * invH;
  }
}

// ================= launch =================
extern "C" void kernel_launch(void* const* d_in, const int* in_sizes, int n_in,
                              void* d_out, int out_size, void* d_ws, size_t ws_size,
                              hipStream_t stream) {
  const float* V    = (const float*)d_in[0];
  const float* Lm   = (const float*)d_in[1];
  const float* O    = (const float*)d_in[2];
  const float* mask = (const float*)d_in[3];
  const float* w1   = (const float*)d_in[4];
  const float* b1   = (const float*)d_in[5];
  const float* w2   = (const float*)d_in[6];
  const float* b2   = (const float*)d_in[7];
  const float* ow   = (const float*)d_in[8];
  const float* ob   = (const float*)d_in[9];
  float* out = (float*)d_out;

  __hip_bfloat16* ws  = (__hip_bfloat16*)d_ws;
  __hip_bfloat16* q1  = ws;
  __hip_bfloat16* q2  = q1 + (size_t)4096*768;
  __hip_bfloat16* k1  = q2 + (size_t)4096*768;
  __hip_bfloat16* v1  = k1 + (size_t)8192*768;
  __hip_bfloat16* k2  = v1 + (size_t)8192*768;
  __hip_bfloat16* v2  = k2 + (size_t)8192*768;
  float* ctx   = (float*)(v2 + (size_t)8192*768);
  float* stats = ctx + (size_t)4096*768;

  hipMemsetAsync(ctx, 0, (size_t)4096*768*4, stream);

  dim3 blk(256);
  gemm_mfma<__hip_bfloat16><<<dim3(64, 12),  blk, 0, stream>>>(O,  w1,             b1,        q1, 4096);
  gemm_mfma<__hip_bfloat16><<<dim3(64, 12),  blk, 0, stream>>>(O,  w2,             b2,        q2, 4096);
  gemm_mfma<__hip_bfloat16><<<dim3(128, 12), blk, 0, stream>>>(V,  w1 + 768*768,   b1 + 768,  k1, 8192);
  gemm_mfma<__hip_bfloat16><<<dim3(128, 12), blk, 0, stream>>>(V,  w1 + 2*768*768, b1 + 1536, v1, 8192);
  gemm_mfma<__hip_bfloat16><<<dim3(128, 12), blk, 0, stream>>>(Lm, w2 + 768*768,   b2 + 768,  k2, 8192);
  gemm_mfma<__hip_bfloat16><<<dim3(128, 12), blk, 0, stream>>>(Lm, w2 + 2*768*768, b2 + 1536, v2, 8192);

  attn_stats<<<dim3(3072), blk, 0, stream>>>(q1, q2, k1, k2, mask, stats);

  hipFuncSetAttribute((const void*)attn_main, hipFuncAttributeMaxDynamicSharedMemorySize, SMEM_MAIN);
  attn_main<<<dim3(1024), dim3(512), SMEM_MAIN, stream>>>(q1, q2, k1, v1, k2, v2, mask, stats,
                                                          ctx, out + (size_t)4096*768);

  gemm_mfma<float><<<dim3(64, 12), blk, 0, stream>>>(ctx, ow, ob, out, 4096);
}

// Round 7
// 543.615 us; speedup vs baseline: 1.7642x; 1.1977x over previous
//
#include <hip/hip_runtime.h>
#include <hip/hip_bf16.h>
#include <type_traits>

#define B_  8
#define LO_ 512
#define E_  768
#define H_  12
#define S_  2048

typedef __attribute__((ext_vector_type(8))) short bf16x8;
typedef __attribute__((ext_vector_type(4))) float f32x4;
#define MFMA16(a,b,c) __builtin_amdgcn_mfma_f32_16x16x32_bf16(a, b, c, 0, 0, 0)

__device__ inline short f2bf(float f) {
  __hip_bfloat16 h = __float2bfloat16(f);
  return *reinterpret_cast<short*>(&h);
}
__device__ inline float bf2f(short s) {
  unsigned int u = ((unsigned int)(unsigned short)s) << 16;
  return __uint_as_float(u);
}

// ================= fp32 -> bf16 bulk convert (memory-bound, 8 elems/thread) ======
__global__ __launch_bounds__(256) void to_bf16(
    const float* __restrict__ in, __hip_bfloat16* __restrict__ out, int n8)
{
  const int i = blockIdx.x * 256 + threadIdx.x;
  if (i >= n8) return;
  const float4* p = (const float4*)(in + (size_t)i * 8);
  const float4 a = p[0], b = p[1];
  short r[8] = { f2bf(a.x), f2bf(a.y), f2bf(a.z), f2bf(a.w),
                 f2bf(b.x), f2bf(b.y), f2bf(b.z), f2bf(b.w) };
  *(bf16x8*)(out + (size_t)i * 8) = *(bf16x8*)r;
}

// ================= bf16 MFMA GEMM: C[r][c] = sum_k A[r][k]*W[c][k] + bias[c] =====
// A: R x 768 bf16, W: 768 x 768 bf16 (row-major, row = out col), C: R x 768 (TC).
// Tile 128(M) x 64(N), BK=64; 256 thr = 4 waves. Wave w: row strips {w*16, 64+w*16},
// all 64 cols -> 16 MFMA / k-step / wave (2x the old 64x64 tile), zero convert VALU.
template <typename TC>
__global__ __launch_bounds__(256) void gemm_bf16(
    const __hip_bfloat16* __restrict__ A, const __hip_bfloat16* __restrict__ W,
    const float* __restrict__ bias, TC* __restrict__ C, int R)
{
  constexpr int N = 768, K = 768;
  __shared__ short As[128*72] __attribute__((aligned(16)));
  __shared__ short Ws[64*72]  __attribute__((aligned(16)));
  const int tid = threadIdx.x, wv = tid >> 6, lane = tid & 63;
  const int quad = lane >> 4, l15 = lane & 15;
  const int r0 = blockIdx.x * 128, c0 = blockIdx.y * 64;
  const int arow = tid >> 1, aks = (tid & 1) * 32;   // A: 128 rows x 64 k, 64 B/thr
  const int wrow = tid >> 2, wks = (tid & 3) * 16;   // W: 64 rows x 64 k, 32 B/thr

  f32x4 acc[2][4] = {};

  for (int k0 = 0; k0 < K; k0 += 64) {
    const __hip_bfloat16* ga = A + (size_t)(r0 + arow) * K + k0 + aks;
    const __hip_bfloat16* gw = W + (size_t)(c0 + wrow) * K + k0 + wks;
    const bf16x8 a0 = *(const bf16x8*)ga;
    const bf16x8 a1 = *(const bf16x8*)(ga + 8);
    const bf16x8 a2 = *(const bf16x8*)(ga + 16);
    const bf16x8 a3 = *(const bf16x8*)(ga + 24);
    const bf16x8 w0 = *(const bf16x8*)gw;
    const bf16x8 w1 = *(const bf16x8*)(gw + 8);
    __syncthreads();   // previous iteration's frag reads complete
    *(bf16x8*)&As[arow*72 + aks]      = a0;
    *(bf16x8*)&As[arow*72 + aks + 8]  = a1;
    *(bf16x8*)&As[arow*72 + aks + 16] = a2;
    *(bf16x8*)&As[arow*72 + aks + 24] = a3;
    *(bf16x8*)&Ws[wrow*72 + wks]      = w0;
    *(bf16x8*)&Ws[wrow*72 + wks + 8]  = w1;
    __syncthreads();

    bf16x8 af[2][2];
#pragma unroll
    for (int s = 0; s < 2; ++s)
#pragma unroll
      for (int kk = 0; kk < 2; ++kk)
        af[s][kk] = *(const bf16x8*)&As[(s*64 + wv*16 + l15)*72 + kk*32 + quad*8];
#pragma unroll
    for (int ct = 0; ct < 4; ++ct) {
      const bf16x8 bf0 = *(const bf16x8*)&Ws[(ct*16 + l15)*72 +      quad*8];
      const bf16x8 bf1 = *(const bf16x8*)&Ws[(ct*16 + l15)*72 + 32 + quad*8];
      acc[0][ct] = MFMA16(af[0][0], bf0, acc[0][ct]);
      acc[0][ct] = MFMA16(af[0][1], bf1, acc[0][ct]);
      acc[1][ct] = MFMA16(af[1][0], bf0, acc[1][ct]);
      acc[1][ct] = MFMA16(af[1][1], bf1, acc[1][ct]);
    }
  }

#pragma unroll
  for (int ct = 0; ct < 4; ++ct) {
    const int col = c0 + ct*16 + l15;
    const float bv = bias[col];
#pragma unroll
    for (int s = 0; s < 2; ++s)
#pragma unroll
      for (int r = 0; r < 4; ++r) {
        const int row = r0 + s*64 + wv*16 + quad*4 + r;   // C: row=quad*4+reg, col=l15
        const float v = acc[s][ct][r] + bv;
        if constexpr (std::is_same_v<TC, float>) C[(size_t)row * N + col] = v;
        else                                     C[(size_t)row * N + col] = __float2bfloat16(v);
      }
  }
}

// ================= stats kernel: per-row softmax (m, 1/l) over full 2048 =========
// (round-2 version: named-register depth-1 pipeline + XCD swizzle — verified fast)
__device__ __forceinline__ void stats_load(
    const __hip_bfloat16* __restrict__ kq, const float* __restrict__ mb, int it,
    bf16x8 (&kb)[4][2], float (&mv)[4][4])
{
#pragma unroll
  for (int ct = 0; ct < 4; ++ct) {
    kb[ct][0] = *(const bf16x8*)(kq + (size_t)ct*16*E_);
    kb[ct][1] = *(const bf16x8*)(kq + (size_t)ct*16*E_ + 32);
#pragma unroll
    for (int r = 0; r < 4; ++r)
      mv[ct][r] = mb[(size_t)r*S_ + it*256 + ct*16];
  }
}

__device__ __forceinline__ void stats_compute(
    const bf16x8 (&qa)[2], const bf16x8 (&kb)[4][2], const float (&mv)[4][4],
    float (&m_l)[4], float (&l_l)[4])
{
  float v[4][4];
#pragma unroll
  for (int ct = 0; ct < 4; ++ct) {
    f32x4 sacc = {};
    sacc = MFMA16(qa[0], kb[ct][0], sacc);
    sacc = MFMA16(qa[1], kb[ct][1], sacc);
#pragma unroll
    for (int r = 0; r < 4; ++r) v[ct][r] = sacc[r]*0.125f + mv[ct][r];
  }
#pragma unroll
  for (int r = 0; r < 4; ++r) {
    const float cm = fmaxf(fmaxf(v[0][r], v[1][r]), fmaxf(v[2][r], v[3][r]));
    const float mn = fmaxf(m_l[r], cm);
    const float add = (__expf(v[0][r]-mn) + __expf(v[1][r]-mn))
                    + (__expf(v[2][r]-mn) + __expf(v[3][r]-mn));
    l_l[r] = l_l[r]*__expf(m_l[r]-mn) + add;
    m_l[r] = mn;
  }
}

__global__ __launch_bounds__(256) void attn_stats(
    const __hip_bfloat16* __restrict__ q1, const __hip_bfloat16* __restrict__ q2,
    const __hip_bfloat16* __restrict__ k1, const __hip_bfloat16* __restrict__ k2,
    const float* __restrict__ mask, float* __restrict__ stats)
{
  __shared__ float smm[4][16], sml[4][16];

  const int tid = threadIdx.x, wv = tid >> 6, lane = tid & 63;
  const int quad = lane >> 4, l15 = lane & 15;
  const int bid = blockIdx.x;
  const int Lid = (bid & 7) * 384 + (bid >> 3);
  const int qt = Lid & 31, h = (Lid >> 5) % 12, b = Lid / 384;
  const int r0 = qt * 16;

  bf16x8 qa0[2], qa1[2];
#pragma unroll
  for (int ks = 0; ks < 2; ++ks) {
    qa0[ks] = *(const bf16x8*)(q1 + ((size_t)(b*LO_ + r0 + l15))*E_ + h*64 + ks*32 + quad*8);
    qa1[ks] = *(const bf16x8*)(q2 + ((size_t)(b*LO_ + r0 + l15))*E_ + h*64 + ks*32 + quad*8);
  }

  const float* mb = mask + (size_t)(r0 + quad*4)*S_ + wv*64 + l15;
  const __hip_bfloat16* kp1 = k1 + ((size_t)(b*1024 + wv*64 + l15))*E_ + h*64 + quad*8;
  const __hip_bfloat16* kp2 = k2 + ((size_t)(b*1024 + wv*64 + l15))*E_ + h*64 + quad*8;

  float m_l[4] = {-3.0e38f, -3.0e38f, -3.0e38f, -3.0e38f};
  float l_l[4] = {};

  bf16x8 kA[4][2], kB[4][2];
  float  mA[4][4], mB[4][4];

  stats_load(kp1 + (size_t)0*256*E_, mb, 0, kA, mA);
  stats_load(kp1 + (size_t)1*256*E_, mb, 1, kB, mB);
  stats_compute(qa0, kA, mA, m_l, l_l);
  stats_load(kp1 + (size_t)2*256*E_, mb, 2, kA, mA);
  stats_compute(qa0, kB, mB, m_l, l_l);
  stats_load(kp1 + (size_t)3*256*E_, mb, 3, kB, mB);
  stats_compute(qa0, kA, mA, m_l, l_l);
  stats_load(kp2 + (size_t)0*256*E_, mb, 4, kA, mA);
  stats_compute(qa0, kB, mB, m_l, l_l);
  stats_load(kp2 + (size_t)1*256*E_, mb, 5, kB, mB);
  stats_compute(qa1, kA, mA, m_l, l_l);
  stats_load(kp2 + (size_t)2*256*E_, mb, 6, kA, mA);
  stats_compute(qa1, kB, mB, m_l, l_l);
  stats_load(kp2 + (size_t)3*256*E_, mb, 7, kB, mB);
  stats_compute(qa1, kA, mA, m_l, l_l);
  stats_compute(qa1, kB, mB, m_l, l_l);

#pragma unroll
  for (int off = 1; off < 16; off <<= 1) {
#pragma unroll
    for (int r = 0; r < 4; ++r) {
      const float mo = __shfl_xor(m_l[r], off, 64);
      const float lo = __shfl_xor(l_l[r], off, 64);
      const float mn = fmaxf(m_l[r], mo);
      l_l[r] = l_l[r]*__expf(m_l[r]-mn) + lo*__expf(mo-mn);
      m_l[r] = mn;
    }
  }
  if (l15 == 0) {
#pragma unroll
    for (int r = 0; r < 4; ++r) { smm[wv][quad*4+r] = m_l[r]; sml[wv][quad*4+r] = l_l[r]; }
  }
  __syncthreads();
  if (tid < 16) {
    float m = smm[0][tid], l = sml[0][tid];
#pragma unroll
    for (int ww = 1; ww < 4; ++ww) {
      const float mo = smm[ww][tid], lo = sml[ww][tid];
      const float mn = fmaxf(m, mo);
      l = l*__expf(m-mn) + lo*__expf(mo-mn);
      m = mn;
    }
    const size_t idx = (((size_t)(b*H_ + h))*LO_ + r0 + tid) * 2;
    stats[idx] = m; stats[idx+1] = 1.0f / l;
  }
}

// ================= main attention (round-6 verified version, unchanged) ==========
#define OFF_VT   0
#define OFF_PST  17408
#define OFF_OBUF 21760
#define SMEM_MAIN 29952

__global__ __launch_bounds__(512, 4) void attn_main(
    const __hip_bfloat16* __restrict__ q1, const __hip_bfloat16* __restrict__ q2,
    const __hip_bfloat16* __restrict__ k1, const __hip_bfloat16* __restrict__ v1,
    const __hip_bfloat16* __restrict__ k2, const __hip_bfloat16* __restrict__ v2,
    const float* __restrict__ mask, const float* __restrict__ stats,
    float* __restrict__ ctx, float* __restrict__ avg)
{
  extern __shared__ char smem[];
  short* vT   = (short*)(smem + OFF_VT);     // [64 dims][136] bf16, key-chunk swizzled
  short* pst  = (short*)(smem + OFF_PST);    // [16][136] bf16
  float* obuf = (float*)(smem + OFF_OBUF);   // [8][256]

  const int tid = threadIdx.x, wv = tid >> 6, lane = tid & 63;
  const int quad = lane >> 4, l15 = lane & 15;
  // XCD swizzle: 1024 blocks = 8 XCD-chunks of 128; batch b == XCD index.
  const int bid = blockIdx.x;
  const int Lid = (bid & 7) * 128 + (bid >> 3);
  const int b = Lid >> 7;
  const int inner = Lid & 127;
  const int src = inner & 1, ks = (inner >> 1) & 1, qt = inner >> 2;
  const int r0 = qt * 16;
  const int kb0 = b*1024 + ks*512;   // first global key row for this block
  const __hip_bfloat16* qws = src ? q2 : q1;
  const __hip_bfloat16* kws = src ? k2 : k1;
  const __hip_bfloat16* vws = src ? v2 : v1;

  const int cpr = wv >> 2;   // 64-key half of the staged 128
  const int ct  = wv & 3;    // 16-wide dim tile
  const int nb  = cpr*64 + ct*16;

  // V staging coords: key row = tid>>2 (0..127), dim base = (tid&3)*16
  const int vrow = tid >> 2, vc16 = (tid & 3) * 16;
  const int vbase = vc16*136 + (((vrow >> 3) ^ ((tid & 3) << 1)) << 3) + (vrow & 7);
  const int dimv = ct*16 + l15;
  const int vr0 = dimv*136 + (((cpr*8 +     quad) ^ (ct << 1)) << 3);
  const int vr1 = dimv*136 + (((cpr*8 + 4 + quad) ^ (ct << 1)) << 3);

  // ---- mask: head-independent, this block's 4 cp chunks, packed bf16 in regs ----
  unsigned int mpk[8];
  {
    const float* mptr = mask + (size_t)(r0 + quad*4)*S_ + src*1024 + ks*512 + nb + l15;
#pragma unroll
    for (int cp = 0; cp < 4; ++cp) {
      const float m0 = mptr[(size_t)0*S_ + cp*128];
      const float m1 = mptr[(size_t)1*S_ + cp*128];
      const float m2 = mptr[(size_t)2*S_ + cp*128];
      const float m3 = mptr[(size_t)3*S_ + cp*128];
      mpk[cp*2]   = (unsigned int)(unsigned short)f2bf(m0) | ((unsigned int)(unsigned short)f2bf(m1) << 16);
      mpk[cp*2+1] = (unsigned int)(unsigned short)f2bf(m2) | ((unsigned int)(unsigned short)f2bf(m3) << 16);
    }
  }

  float pacc[4][4] = {};   // [cp][r] — cp always a literal (unrolled macro)

  bf16x8 vA0, vA1, vB0, vB1;

#define CP_BODY(CP, VC0, VC1, VN0, VN1)                                              \
  {                                                                                  \
    __syncthreads();  /* prev cp's PV reads of vT/pst complete */                    \
    /* K inline: issue load first, consume after the ds_writes below */              \
    const __hip_bfloat16* kp = kws + ((size_t)(kb0 + (CP)*128 + nb + l15))*E_ + h*64 + quad*8; \
    const bf16x8 kc0 = *(const bf16x8*)kp;                                           \
    const bf16x8 kc1 = *(const bf16x8*)(kp + 32);                                    \
    _Pragma("unroll")                                                                \
    for (int i = 0; i < 8; ++i) vT[vbase + i*136]     = VC0[i];                      \
    _Pragma("unroll")                                                                \
    for (int i = 0; i < 8; ++i) vT[vbase + (i+8)*136] = VC1[i];                      \
    if ((CP) < 3) {  /* prefetch next chunk's V */                                   \
      const bf16x8* gv = (const bf16x8*)(vws + ((size_t)(kb0 + ((CP)+1)*128 + vrow))*E_ + h*64 + vc16); \
      VN0 = gv[0]; VN1 = gv[1];                                                      \
    }                                                                                \
    {                                                                                \
      f32x4 sacc = {};                                                               \
      sacc = MFMA16(qa0, kc0, sacc);                                                 \
      sacc = MFMA16(qa1, kc1, sacc);                                                 \
      const unsigned int w0 = mpk[(CP)*2], w1 = mpk[(CP)*2+1];                       \
      float mr[4];                                                                   \
      mr[0] = bf2f((short)(w0 & 0xffff)); mr[1] = bf2f((short)(w0 >> 16));           \
      mr[2] = bf2f((short)(w1 & 0xffff)); mr[3] = bf2f((short)(w1 >> 16));           \
      _Pragma("unroll")                                                              \
      for (int r = 0; r < 4; ++r) {                                                  \
        const float p = __expf(sacc[r]*0.125f + mr[r] - m_r[r]) * il_r[r];           \
        pacc[CP][r] += p;                                                            \
        pst[(quad*4 + r)*136 + nb + l15] = f2bf(p);                                  \
      }                                                                              \
    }                                                                                \
    __syncthreads();  /* vT + pst visible */                                         \
    {                                                                                \
      const bf16x8 pa0 = *(const bf16x8*)&pst[l15*136 + cpr*64 +      quad*8];       \
      const bf16x8 pa1 = *(const bf16x8*)&pst[l15*136 + cpr*64 + 32 + quad*8];       \
      const bf16x8 vb0 = *(const bf16x8*)&vT[vr0];                                   \
      const bf16x8 vb1 = *(const bf16x8*)&vT[vr1];                                   \
      oacc = MFMA16(pa0, vb0, oacc);                                                 \
      oacc = MFMA16(pa1, vb1, oacc);                                                 \
    }                                                                                \
  }

#pragma unroll 1
  for (int h = 0; h < H_; ++h) {
    // Q fragments + stats direct from global
    const __hip_bfloat16* qp = qws + ((size_t)(b*LO_ + r0 + l15))*E_ + h*64 + quad*8;
    const bf16x8 qa0 = *(const bf16x8*)qp;
    const bf16x8 qa1 = *(const bf16x8*)(qp + 32);

    float m_r[4], il_r[4];
#pragma unroll
    for (int r = 0; r < 4; ++r) {
      const size_t idx = (((size_t)(b*H_ + h))*LO_ + r0 + quad*4 + r) * 2;
      m_r[r] = stats[idx]; il_r[r] = stats[idx+1];
    }

    // preload V(0) for this head
    {
      const bf16x8* gv = (const bf16x8*)(vws + ((size_t)(kb0 + vrow))*E_ + h*64 + vc16);
      vA0 = gv[0]; vA1 = gv[1];
    }

    f32x4 oacc = {};

    CP_BODY(0, vA0, vA1, vB0, vB1)
    CP_BODY(1, vB0, vB1, vA0, vA1)
    CP_BODY(2, vA0, vA1, vB0, vB1)
    CP_BODY(3, vB0, vB1, vA0, vA1)

    // ---- merge wave pairs (wv, wv+4) and accumulate ctx ----
    __syncthreads();   // PV reads of vT/pst done; order waves before obuf writes
#pragma unroll
    for (int r = 0; r < 4; ++r) obuf[wv*256 + r*64 + lane] = oacc[r];
    __syncthreads();
#pragma unroll
    for (int e0 = 0; e0 < 2; ++e0) {
      const int e = tid + e0*512;
      const int row = e >> 6, dim = e & 63;
      const int idx = (row & 3)*64 + (row >> 2)*16 + (dim & 15);
      const float v = obuf[(dim >> 4)*256 + idx] + obuf[((dim >> 4) + 4)*256 + idx];
      atomicAdd(&ctx[((size_t)(b*LO_ + r0 + row))*E_ + h*64 + dim], v);
    }
  }
#undef CP_BODY

  // ---- write head-averaged attention (fp32) from registers (disjoint columns) ----
  {
    constexpr float invH = 1.0f / 12.0f;
#pragma unroll
    for (int cp = 0; cp < 4; ++cp)
#pragma unroll
      for (int r = 0; r < 4; ++r)
        avg[(size_t)(b*LO_ + r0 + quad*4 + r)*S_ + src*1024 + ks*512 + cp*128 + nb + l15]
            = pacc[cp][r] * invH;
  }
}

// ================= launch =================
extern "C" void kernel_launch(void* const* d_in, const int* in_sizes, int n_in,
                              void* d_out, int out_size, void* d_ws, size_t ws_size,
                              hipStream_t stream) {
  const float* V    = (const float*)d_in[0];
  const float* Lm   = (const float*)d_in[1];
  const float* O    = (const float*)d_in[2];
  const float* mask = (const float*)d_in[3];
  const float* w1   = (const float*)d_in[4];
  const float* b1   = (const float*)d_in[5];
  const float* w2   = (const float*)d_in[6];
  const float* b2   = (const float*)d_in[7];
  const float* ow   = (const float*)d_in[8];
  const float* ob   = (const float*)d_in[9];
  float* out = (float*)d_out;

  // ws layout (bf16 unless noted). scratch bf16 region ALIASES ctx fp32 region
  // (8192*768*2B == 4096*768*4B exactly); sequencing via stream order:
  //   conv(X -> scr) ... gemms reading scr ... next conv overwrites scr ...
  //   memset ctx (== scr) only after the q-GEMMs.
  __hip_bfloat16* ws  = (__hip_bfloat16*)d_ws;
  __hip_bfloat16* q1  = ws;
  __hip_bfloat16* q2  = q1 + (size_t)4096*768;
  __hip_bfloat16* k1  = q2 + (size_t)4096*768;
  __hip_bfloat16* v1  = k1 + (size_t)8192*768;
  __hip_bfloat16* k2  = v1 + (size_t)8192*768;
  __hip_bfloat16* v2  = k2 + (size_t)8192*768;
  float* ctx   = (float*)(v2 + (size_t)8192*768);          // 4096*768 fp32
  float* stats = ctx + (size_t)4096*768;                   // 8*12*512*2 fp32
  __hip_bfloat16* w1b  = (__hip_bfloat16*)(stats + (size_t)8*12*512*2);  // 3*768*768
  __hip_bfloat16* w2b  = w1b + (size_t)3*768*768;
  __hip_bfloat16* owb  = w2b + (size_t)3*768*768;          // 768*768
  __hip_bfloat16* ctxb = owb + (size_t)768*768;            // 4096*768
  __hip_bfloat16* scr  = (__hip_bfloat16*)ctx;             // aliases ctx

  dim3 blk(256);
  const int W8 = 768*768/8;

  // weights -> bf16 (once)
  to_bf16<<<dim3((3*W8 + 255)/256), blk, 0, stream>>>(w1, w1b, 3*W8);
  to_bf16<<<dim3((3*W8 + 255)/256), blk, 0, stream>>>(w2, w2b, 3*W8);
  to_bf16<<<dim3((W8   + 255)/256), blk, 0, stream>>>(ow, owb, W8);

  // V -> scr; K1/V1 projections
  to_bf16<<<dim3(8192*768/8/256), blk, 0, stream>>>(V, scr, 8192*768/8);
  gemm_bf16<__hip_bfloat16><<<dim3(64, 12), blk, 0, stream>>>(scr, w1b +   768*768, b1 + 768,  k1, 8192);
  gemm_bf16<__hip_bfloat16><<<dim3(64, 12), blk, 0, stream>>>(scr, w1b + 2*768*768, b1 + 1536, v1, 8192);
  // L -> scr; K2/V2 projections
  to_bf16<<<dim3(8192*768/8/256), blk, 0, stream>>>(Lm, scr, 8192*768/8);
  gemm_bf16<__hip_bfloat16><<<dim3(64, 12), blk, 0, stream>>>(scr, w2b +   768*768, b2 + 768,  k2, 8192);
  gemm_bf16<__hip_bfloat16><<<dim3(64, 12), blk, 0, stream>>>(scr, w2b + 2*768*768, b2 + 1536, v2, 8192);
  // O -> scr; Q projections
  to_bf16<<<dim3(4096*768/8/256), blk, 0, stream>>>(O, scr, 4096*768/8);
  gemm_bf16<__hip_bfloat16><<<dim3(32, 12), blk, 0, stream>>>(scr, w1b, b1, q1, 4096);
  gemm_bf16<__hip_bfloat16><<<dim3(32, 12), blk, 0, stream>>>(scr, w2b, b2, q2, 4096);

  // ctx (== scr) free now
  hipMemsetAsync(ctx, 0, (size_t)4096*768*4, stream);

  attn_stats<<<dim3(3072), blk, 0, stream>>>(q1, q2, k1, k2, mask, stats);

  hipFuncSetAttribute((const void*)attn_main, hipFuncAttributeMaxDynamicSharedMemorySize, SMEM_MAIN);
  attn_main<<<dim3(1024), dim3(512), SMEM_MAIN, stream>>>(q1, q2, k1, v1, k2, v2, mask, stats,
                                                          ctx, out + (size_t)4096*768);

  // ctx -> bf16; output projection
  to_bf16<<<dim3(4096*768/8/256), blk, 0, stream>>>(ctx, ctxb, 4096*768/8);
  gemm_bf16<float><<<dim3(32, 12), blk, 0, stream>>>(ctxb, owb, ob, out, 4096);
}